// Round 1
// baseline (660.706 us; speedup 1.0000x reference)
//
#include <hip/hip_runtime.h>
#include <math.h>

#define NEG_INF -1000000000.0f

// Problem constants (from reference setup_inputs)
#define B_  32
#define S_  128
#define WL_ 20
#define D1_ 300
#define D2_ 300
#define OUT_ 300
#define BS_ (B_ * S_)          // 4096 blocks
#define KTOT_ (D1_ + D2_)      // 600

// Transposed weights: Wt[k][o] = W[o][k], k in [0,600), o in [0,300)
__device__ float g_Wt[KTOT_ * OUT_];

__global__ void transpose_W(const float* __restrict__ W) {
    int tid = blockIdx.x * blockDim.x + threadIdx.x;
    if (tid < KTOT_ * OUT_) {
        int k = tid / OUT_;
        int o = tid - k * OUT_;
        g_Wt[tid] = W[o * KTOT_ + k];
    }
}

__global__ __launch_bounds__(320) void attn_kernel(
    const float* __restrict__ seq,   // [B,S,WL,D1]
    const float* __restrict__ vec,   // [B,S,D2]
    const int*   __restrict__ masks, // [B,S,WL]
    const float* __restrict__ bvec,  // [OUT]
    const float* __restrict__ vvec,  // [OUT]
    float*       __restrict__ out)   // [B,S,D1]
{
    __shared__ float seq_lds[WL_ * D1_];   // 24000 B
    __shared__ float vec_lds[D2_];
    __shared__ int   mask_lds[WL_];
    __shared__ float partial[5][WL_];
    __shared__ float score_lds[WL_];

    const int t  = threadIdx.x;
    const int bs = blockIdx.x;

    // ---- stage sequence tile + vector into LDS (contiguous, float4) ----
    const float4* seq_g4 = (const float4*)(seq + (size_t)bs * (WL_ * D1_));
    float4* seq_l4 = (float4*)seq_lds;
    for (int i = t; i < (WL_ * D1_) / 4; i += 320) seq_l4[i] = seq_g4[i];

    const float4* vec_g4 = (const float4*)(vec + (size_t)bs * D2_);
    float4* vec_l4 = (float4*)vec_lds;
    if (t < D2_ / 4) vec_l4[t] = vec_g4[t];

    if (t < WL_) mask_lds[t] = masks[bs * WL_ + t];
    __syncthreads();

    const bool active = (t < OUT_);
    const int  o = active ? t : 0;

    // ---- vector-side linear: vlin = b[o] + sum_d vec[d] * Wv[o][d] ----
    float vlin = bvec[o];
    for (int d4 = 0; d4 < D2_ / 4; ++d4) {
        float4 v4 = vec_l4[d4];
        float w0 = g_Wt[(D1_ + d4 * 4 + 0) * OUT_ + o];
        float w1 = g_Wt[(D1_ + d4 * 4 + 1) * OUT_ + o];
        float w2 = g_Wt[(D1_ + d4 * 4 + 2) * OUT_ + o];
        float w3 = g_Wt[(D1_ + d4 * 4 + 3) * OUT_ + o];
        vlin += v4.x * w0 + v4.y * w1 + v4.z * w2 + v4.w * w3;
    }

    // ---- sequence-side linear: lin[w] = vlin + sum_d seq[w][d] * Ws[o][d] ----
    float lin[WL_];
    #pragma unroll
    for (int w = 0; w < WL_; ++w) lin[w] = vlin;

    for (int d4 = 0; d4 < D1_ / 4; ++d4) {
        float w0 = g_Wt[(d4 * 4 + 0) * OUT_ + o];
        float w1 = g_Wt[(d4 * 4 + 1) * OUT_ + o];
        float w2 = g_Wt[(d4 * 4 + 2) * OUT_ + o];
        float w3 = g_Wt[(d4 * 4 + 3) * OUT_ + o];
        #pragma unroll
        for (int w = 0; w < WL_; ++w) {
            float4 s4 = *(const float4*)(seq_lds + w * D1_ + d4 * 4);
            lin[w] += s4.x * w0 + s4.y * w1 + s4.z * w2 + s4.w * w3;
        }
    }

    // ---- per-thread score contribution: tanh(lin[w]) * v[o] ----
    const float vo = active ? vvec[o] : 0.0f;
    float c[WL_];
    #pragma unroll
    for (int w = 0; w < WL_; ++w) c[w] = active ? tanhf(lin[w]) * vo : 0.0f;

    // ---- deterministic block reduction over o ----
    #pragma unroll
    for (int w = 0; w < WL_; ++w) {
        float val = c[w];
        #pragma unroll
        for (int off = 32; off > 0; off >>= 1)
            val += __shfl_down(val, off, 64);
        c[w] = val;
    }
    const int lane = t & 63, wave = t >> 6;
    if (lane == 0) {
        #pragma unroll
        for (int w = 0; w < WL_; ++w) partial[wave][w] = c[w];
    }
    __syncthreads();
    if (t < WL_) {
        float s = 0.0f;
        #pragma unroll
        for (int wv = 0; wv < 5; ++wv) s += partial[wv][t];
        score_lds[t] = s;
    }
    __syncthreads();

    // ---- masked softmax (redundant per thread, all in registers) ----
    float sc[WL_];
    float m = -INFINITY;
    #pragma unroll
    for (int w = 0; w < WL_; ++w) {
        sc[w] = (mask_lds[w] == 0) ? NEG_INF : score_lds[w];
        m = fmaxf(m, sc[w]);
    }
    float sum = 0.0f;
    #pragma unroll
    for (int w = 0; w < WL_; ++w) { sc[w] = __expf(sc[w] - m); sum += sc[w]; }
    const float inv = 1.0f / sum;

    // ---- weighted sum over w: out[bs][d] with d = t ----
    if (active) {
        float acc = 0.0f;
        #pragma unroll
        for (int w = 0; w < WL_; ++w)
            acc += sc[w] * seq_lds[w * D1_ + t];
        out[(size_t)bs * D1_ + t] = acc * inv;
    }
}

extern "C" void kernel_launch(void* const* d_in, const int* in_sizes, int n_in,
                              void* d_out, int out_size, void* d_ws, size_t ws_size,
                              hipStream_t stream) {
    const float* seq   = (const float*)d_in[0];
    const float* vec   = (const float*)d_in[1];
    const int*   masks = (const int*)d_in[2];
    const float* W     = (const float*)d_in[3];
    const float* b     = (const float*)d_in[4];
    const float* v     = (const float*)d_in[5];
    float* out = (float*)d_out;

    transpose_W<<<(KTOT_ * OUT_ + 255) / 256, 256, 0, stream>>>(W);
    attn_kernel<<<BS_, 320, 0, stream>>>(seq, vec, masks, b, v, out);
}

// Round 2
// 320.688 us; speedup vs baseline: 2.0603x; 2.0603x over previous
//
#include <hip/hip_runtime.h>
#include <math.h>

#define NEG_INF -1000000000.0f

// Problem constants
#define B_   32
#define S_   128
#define WL_  20
#define D1_  300
#define D2_  300
#define OUT_ 300
#define BS_  (B_ * S_)               // 4096 (b,s) pairs
#define PPB  8                        // pairs per block
#define NBLK (BS_ / PPB)              // 512 blocks
#define BM   160                      // 8 pairs * 20 rows
#define BN   320                      // 300 padded to 320 (20 tiles)
#define BK   32
#define KTOT 608                      // 600 padded to 608
#define KSTEPS (KTOT / BK)            // 19
#define LDA  40                       // LDS row stride in shorts (32 + 8 pad)
#define LDB  40

typedef __attribute__((ext_vector_type(8))) short bf16x8;
typedef __attribute__((ext_vector_type(4))) float f32x4;
typedef __attribute__((ext_vector_type(4))) short short4v;

__device__ inline short f2bf(float f) {
    // round-to-nearest-even fp32 -> bf16 (inputs are finite)
    unsigned u = __float_as_uint(f);
    u += 0x7FFFu + ((u >> 16) & 1u);
    return (short)(u >> 16);
}

__global__ __launch_bounds__(512) void attn_mfma(
    const float* __restrict__ seq,   // [4096,20,300]
    const float* __restrict__ vec,   // [4096,300]
    const int*   __restrict__ masks, // [4096,20]
    const float* __restrict__ W,     // [300,600]  (B col o = W[o][:], no transpose needed)
    const float* __restrict__ bvec,  // [300]
    const float* __restrict__ vvec,  // [300]
    float*       __restrict__ out)   // [4096,300]
{
    __shared__ short Alds[BM * LDA];      // 12800 B
    __shared__ short Blds[BN * LDB];      // 25600 B
    __shared__ float sp[4][BM];           // cross-wave score partials
    __shared__ float score_lds[BM];
    __shared__ float alpha_lds[BM];

    const int tid  = threadIdx.x;
    const int lane = tid & 63;
    const int wv   = tid >> 6;      // 0..7
    const int wm   = wv >> 2;       // 0..1  (M group: 80 rows each)
    const int wn   = wv & 3;        // 0..3  (N group: 80 cols each)
    const int ln15 = lane & 15;
    const int q    = lane >> 4;     // 0..3
    const int bpair0 = blockIdx.x * PPB;

    f32x4 acc[5][5];
    #pragma unroll
    for (int i = 0; i < 5; ++i)
        #pragma unroll
        for (int j = 0; j < 5; ++j)
            acc[i][j] = {0.f, 0.f, 0.f, 0.f};

    const size_t seq_row0 = (size_t)bpair0 * WL_;   // first seq row of this block

    for (int ks = 0; ks < KSTEPS; ++ks) {
        const int k0 = ks * BK;
        __syncthreads();   // previous compute done before overwrite

        // ---- stage A slice: 160 rows x 32 k (concat seq|vec|0), fp32->bf16 ----
        // 1280 float4 slots
        for (int f = tid; f < BM * 8; f += 512) {
            const int row = f >> 3;          // 0..159
            const int k4  = f & 7;
            const int k   = k0 + k4 * 4;
            float4 val;
            if (k < D1_) {
                val = *(const float4*)(seq + (seq_row0 + row) * D1_ + k);
            } else if (k < D1_ + D2_) {
                const int pair = (unsigned)row / WL_;
                val = *(const float4*)(vec + (size_t)(bpair0 + pair) * D2_ + (k - D1_));
            } else {
                val = {0.f, 0.f, 0.f, 0.f};
            }
            short4v sv;
            sv.x = f2bf(val.x); sv.y = f2bf(val.y);
            sv.z = f2bf(val.z); sv.w = f2bf(val.w);
            *(short4v*)(&Alds[row * LDA + k4 * 4]) = sv;
        }

        // ---- stage B slice: 320 cols x 32 k from W[o][k], zero-pad ----
        // 2560 float4 slots
        for (int f = tid; f < BN * 8; f += 512) {
            const int o  = f >> 3;           // 0..319
            const int k4 = f & 7;
            const int k  = k0 + k4 * 4;
            float4 val = {0.f, 0.f, 0.f, 0.f};
            if (o < OUT_ && k < (D1_ + D2_))
                val = *(const float4*)(W + (size_t)o * (D1_ + D2_) + k);
            short4v sv;
            sv.x = f2bf(val.x); sv.y = f2bf(val.y);
            sv.z = f2bf(val.z); sv.w = f2bf(val.w);
            *(short4v*)(&Blds[o * LDB + k4 * 4]) = sv;
        }

        __syncthreads();

        // ---- fragments + MFMA ----
        bf16x8 a[5], b[5];
        const short* Abase = Alds + (wm * 80 + ln15) * LDA + q * 8;
        const short* Bbase = Blds + (wn * 80 + ln15) * LDB + q * 8;
        #pragma unroll
        for (int i = 0; i < 5; ++i) a[i] = *(const bf16x8*)(Abase + i * 16 * LDA);
        #pragma unroll
        for (int j = 0; j < 5; ++j) b[j] = *(const bf16x8*)(Bbase + j * 16 * LDB);
        #pragma unroll
        for (int i = 0; i < 5; ++i)
            #pragma unroll
            for (int j = 0; j < 5; ++j)
                acc[i][j] = __builtin_amdgcn_mfma_f32_16x16x32_bf16(a[i], b[j], acc[i][j], 0, 0, 0);
    }

    // ---- epilogue: score[r] = sum_o tanh(lin[r][o]) * v[o] ----
    // C/D layout: col = lane&15, row(within tile) = q*4 + reg
    float vj[5], bj[5];
    #pragma unroll
    for (int j = 0; j < 5; ++j) {
        const int o = wn * 80 + j * 16 + ln15;
        const bool ok = (o < OUT_);
        vj[j] = ok ? vvec[o] : 0.f;
        bj[j] = ok ? bvec[o] : 0.f;
    }
    #pragma unroll
    for (int i = 0; i < 5; ++i) {
        float rs[4] = {0.f, 0.f, 0.f, 0.f};
        #pragma unroll
        for (int j = 0; j < 5; ++j) {
            #pragma unroll
            for (int r = 0; r < 4; ++r) {
                const float x = acc[i][j][r] + bj[j];
                const float e = __expf(2.f * x);       // tanh(x) = 1 - 2/(e^{2x}+1)
                const float t = 1.f - 2.f / (e + 1.f);
                rs[r] += t * vj[j];
            }
        }
        #pragma unroll
        for (int r = 0; r < 4; ++r) {
            float s = rs[r];
            s += __shfl_xor(s, 1, 64);
            s += __shfl_xor(s, 2, 64);
            s += __shfl_xor(s, 4, 64);
            s += __shfl_xor(s, 8, 64);   // sum over 16 cols of the tile
            if (ln15 == 0)
                sp[wn][wm * 80 + i * 16 + q * 4 + r] = s;
        }
    }
    __syncthreads();

    // deterministic cross-wave (N-group) sum
    if (tid < BM)
        score_lds[tid] = sp[0][tid] + sp[1][tid] + sp[2][tid] + sp[3][tid];
    __syncthreads();

    // ---- masked softmax, one thread per pair ----
    if (tid < PPB) {
        const int gp = bpair0 + tid;
        float sc[WL_];
        float m = -INFINITY;
        #pragma unroll
        for (int w = 0; w < WL_; ++w) {
            const int mk = masks[(size_t)gp * WL_ + w];
            float s = (mk == 0) ? NEG_INF : score_lds[tid * WL_ + w];
            sc[w] = s;
            m = fmaxf(m, s);
        }
        float sum = 0.f;
        #pragma unroll
        for (int w = 0; w < WL_; ++w) { sc[w] = __expf(sc[w] - m); sum += sc[w]; }
        const float inv = 1.f / sum;
        #pragma unroll
        for (int w = 0; w < WL_; ++w) alpha_lds[tid * WL_ + w] = sc[w] * inv;
    }
    __syncthreads();

    // ---- weighted sum: out[pair][d] = sum_w alpha * seq (fp32 re-read) ----
    for (int idx = tid; idx < PPB * (D1_ / 4); idx += 512) {
        const int pair = idx / (D1_ / 4);
        const int d4   = idx % (D1_ / 4);
        const int gp   = bpair0 + pair;
        const float* srow = seq + (size_t)gp * WL_ * D1_ + d4 * 4;
        float4 o4 = {0.f, 0.f, 0.f, 0.f};
        #pragma unroll
        for (int w = 0; w < WL_; ++w) {
            const float a = alpha_lds[pair * WL_ + w];
            const float4 s4 = *(const float4*)(srow + w * D1_);
            o4.x += a * s4.x; o4.y += a * s4.y;
            o4.z += a * s4.z; o4.w += a * s4.w;
        }
        *(float4*)(out + (size_t)gp * D1_ + d4 * 4) = o4;
    }
}

extern "C" void kernel_launch(void* const* d_in, const int* in_sizes, int n_in,
                              void* d_out, int out_size, void* d_ws, size_t ws_size,
                              hipStream_t stream) {
    const float* seq   = (const float*)d_in[0];
    const float* vec   = (const float*)d_in[1];
    const int*   masks = (const int*)d_in[2];
    const float* W     = (const float*)d_in[3];
    const float* b     = (const float*)d_in[4];
    const float* v     = (const float*)d_in[5];
    float* out = (float*)d_out;

    attn_mfma<<<NBLK, 512, 0, stream>>>(seq, vec, masks, W, b, v, out);
}

// Round 3
// 282.582 us; speedup vs baseline: 2.3381x; 1.1349x over previous
//
#include <hip/hip_runtime.h>
#include <math.h>

#define NEG_INF -1000000000.0f

// Problem constants
#define B_   32
#define S_   128
#define WL_  20
#define D1_  300
#define D2_  300
#define OUT_ 300
#define BS_  (B_ * S_)          // 4096 (b,s) pairs
#define PPB  8                   // pairs per block
#define NBLK (BS_ / PPB)         // 512 blocks
#define BM   160                 // 8 pairs * 20 rows
#define BN   320                 // 300 padded to 320
#define BK   32
#define KS_  20                  // k-steps over K=640 (seq 320 | vec 320)
#define KA   320                 // padded K per part

typedef __attribute__((ext_vector_type(8))) short bf16x8;
typedef __attribute__((ext_vector_type(8))) short short8v;
typedef __attribute__((ext_vector_type(4))) float f32x4;

// bf16 device globals built by prep each call
__device__ short g_Apre[(size_t)BS_ * WL_ * KA];  // [81920][320] seq bf16, k-pad 0
__device__ short g_vecb[(size_t)BS_ * KA];        // [4096][320]  vec bf16, [319]=1.0
__device__ short g_Wb[(size_t)BN * (2 * KA)];     // [320][640]   [Ws|0|Wv|0|b]

__device__ inline short f2bf(float f) {
    unsigned u = __float_as_uint(f);
    u += 0x7FFFu + ((u >> 16) & 1u);   // RNE
    return (short)(u >> 16);
}

#define SEQ_CHUNKS (BS_ * WL_ * (KA / 8))            // 3,276,800
#define VEC_CHUNKS (BS_ * (KA / 8))                  // 163,840
#define W_CHUNKS   (BN * (2 * KA / 8))               // 25,600
#define TOT_CHUNKS (SEQ_CHUNKS + VEC_CHUNKS + W_CHUNKS)

__global__ __launch_bounds__(256) void prep(
    const float* __restrict__ seq, const float* __restrict__ vec,
    const float* __restrict__ W,   const float* __restrict__ bias)
{
    int id = blockIdx.x * 256 + threadIdx.x;
    if (id >= TOT_CHUNKS) return;
    short8v o8;
    if (id < SEQ_CHUNKS) {
        const int row = id / (KA / 8), j = id % (KA / 8);
        const float* src = seq + (size_t)row * D1_;
        #pragma unroll
        for (int e = 0; e < 8; ++e) {
            const int k = j * 8 + e;
            o8[e] = (k < D1_) ? f2bf(src[k]) : (short)0;
        }
        *(short8v*)(g_Apre + (size_t)row * KA + j * 8) = o8;
    } else if (id < SEQ_CHUNKS + VEC_CHUNKS) {
        const int idv = id - SEQ_CHUNKS;
        const int p = idv / (KA / 8), j = idv % (KA / 8);
        const float* src = vec + (size_t)p * D2_;
        #pragma unroll
        for (int e = 0; e < 8; ++e) {
            const int k = j * 8 + e;
            short val = 0;
            if (k < D2_) val = f2bf(src[k]);
            else if (k == KA - 1) val = (short)0x3F80;   // 1.0 bf16 (bias column)
            o8[e] = val;
        }
        *(short8v*)(g_vecb + (size_t)p * KA + j * 8) = o8;
    } else {
        const int idw = id - SEQ_CHUNKS - VEC_CHUNKS;
        const int o = idw / (2 * KA / 8), j = idw % (2 * KA / 8);
        #pragma unroll
        for (int e = 0; e < 8; ++e) {
            const int kk = j * 8 + e;
            short val = 0;
            if (o < OUT_) {
                if (kk < D1_)                       val = f2bf(W[(size_t)o * (D1_ + D2_) + kk]);
                else if (kk >= KA && kk < KA + D2_) val = f2bf(W[(size_t)o * (D1_ + D2_) + D1_ + (kk - KA)]);
                else if (kk == 2 * KA - 1)          val = f2bf(bias[o]);
            }
            o8[e] = val;
        }
        *(short8v*)(g_Wb + (size_t)o * (2 * KA) + j * 8) = o8;
    }
}

__device__ inline void gl_lds16(const short* g, short* l) {
    __builtin_amdgcn_global_load_lds(
        (const __attribute__((address_space(1))) unsigned int*)g,
        (__attribute__((address_space(3))) unsigned int*)l, 16, 0, 0);
}

__global__ __launch_bounds__(512, 2) void attn_mfma(
    const float* __restrict__ seq,   // fp32, for exact weighted-sum epilogue
    const int*   __restrict__ masks,
    const float* __restrict__ vvec,
    float*       __restrict__ out)
{
    __shared__ short Alds[2][BM * BK];   // 2*10240 B
    __shared__ short Blds[2][BN * BK];   // 2*20480 B
    __shared__ float sp[4][BM];
    __shared__ float score_lds[BM];
    __shared__ float alpha_lds[BM];      // total 65,280 B

    const int tid  = threadIdx.x;
    const int lane = tid & 63;
    const int wv   = tid >> 6;
    const int wm   = wv >> 2;       // 0..1
    const int wn   = wv & 3;        // 0..3
    const int ln15 = lane & 15;
    const int q    = lane >> 4;     // 0..3
    const int bpair0 = blockIdx.x * PPB;

    f32x4 acc[5][5];
    #pragma unroll
    for (int i = 0; i < 5; ++i)
        #pragma unroll
        for (int j = 0; j < 5; ++j) acc[i][j] = {0.f, 0.f, 0.f, 0.f};

    // stage k-step ks into buffer buf (pure DMA, swizzled global fetch)
    auto stage = [&](int ks, int buf) {
        // A: 160 rows x 32k = 640 16B-slots
        for (int f = tid; f < BM * (BK / 8); f += 512) {
            const int row = f >> 2, pos = f & 3;
            const int g = pos ^ ((row >> 1) & 3);   // XOR swizzle (2-way max on frag reads)
            const short* src;
            if (ks < 10) {
                src = g_Apre + (size_t)(bpair0 * WL_ + row) * KA + ks * BK + g * 8;
            } else {
                src = g_vecb + (size_t)(bpair0 + row / WL_) * KA + (ks - 10) * BK + g * 8;
            }
            gl_lds16(src, &Alds[buf][f * 8]);
        }
        // B: 320 cols x 32k = 1280 16B-slots
        for (int f = tid; f < BN * (BK / 8); f += 512) {
            const int o = f >> 2, pos = f & 3;
            const int g = pos ^ ((o >> 1) & 3);
            gl_lds16(g_Wb + (size_t)o * (2 * KA) + ks * BK + g * 8, &Blds[buf][f * 8]);
        }
    };

    stage(0, 0);
    for (int ks = 0; ks < KS_; ++ks) {
        __syncthreads();                      // drains vmcnt: buf[ks&1] ready
        if (ks + 1 < KS_) stage(ks + 1, (ks + 1) & 1);

        const short* Ab = &Alds[ks & 1][0];
        const short* Bb = &Blds[ks & 1][0];
        bf16x8 a[5], b[5];
        #pragma unroll
        for (int i = 0; i < 5; ++i) {
            const int r = wm * 80 + i * 16 + ln15;
            const int pos = q ^ ((r >> 1) & 3);
            a[i] = *(const bf16x8*)(Ab + r * BK + pos * 8);
        }
        #pragma unroll
        for (int j = 0; j < 5; ++j) {
            const int o = wn * 80 + j * 16 + ln15;
            const int pos = q ^ ((o >> 1) & 3);
            b[j] = *(const bf16x8*)(Bb + o * BK + pos * 8);
        }
        #pragma unroll
        for (int i = 0; i < 5; ++i)
            #pragma unroll
            for (int j = 0; j < 5; ++j)
                acc[i][j] = __builtin_amdgcn_mfma_f32_16x16x32_bf16(a[i], b[j], acc[i][j], 0, 0, 0);
    }

    // ---- epilogue: score[r] = sum_o tanh(lin) * v[o]  (bias already in lin) ----
    float vj[5];
    #pragma unroll
    for (int j = 0; j < 5; ++j) {
        const int o = wn * 80 + j * 16 + ln15;
        vj[j] = (o < OUT_) ? vvec[o] : 0.f;
    }
    #pragma unroll
    for (int i = 0; i < 5; ++i) {
        float rs[4] = {0.f, 0.f, 0.f, 0.f};
        #pragma unroll
        for (int j = 0; j < 5; ++j) {
            #pragma unroll
            for (int r = 0; r < 4; ++r) {
                const float x = acc[i][j][r];
                const float e = __expf(2.f * x);
                rs[r] += (1.f - 2.f / (e + 1.f)) * vj[j];
            }
        }
        #pragma unroll
        for (int r = 0; r < 4; ++r) {
            float s = rs[r];
            s += __shfl_xor(s, 1, 64);
            s += __shfl_xor(s, 2, 64);
            s += __shfl_xor(s, 4, 64);
            s += __shfl_xor(s, 8, 64);
            if (ln15 == 0) sp[wn][wm * 80 + i * 16 + q * 4 + r] = s;
        }
    }
    __syncthreads();
    if (tid < BM) score_lds[tid] = sp[0][tid] + sp[1][tid] + sp[2][tid] + sp[3][tid];
    __syncthreads();

    if (tid < PPB) {
        const int gp = bpair0 + tid;
        float sc[WL_];
        float m = -INFINITY;
        #pragma unroll
        for (int w = 0; w < WL_; ++w) {
            const int mk = masks[(size_t)gp * WL_ + w];
            float s = (mk == 0) ? NEG_INF : score_lds[tid * WL_ + w];
            sc[w] = s;
            m = fmaxf(m, s);
        }
        float sum = 0.f;
        #pragma unroll
        for (int w = 0; w < WL_; ++w) { sc[w] = __expf(sc[w] - m); sum += sc[w]; }
        const float inv = 1.f / sum;
        #pragma unroll
        for (int w = 0; w < WL_; ++w) alpha_lds[tid * WL_ + w] = sc[w] * inv;
    }
    __syncthreads();

    // ---- weighted sum from fp32 seq (L3-hot) ----
    for (int idx = tid; idx < PPB * (D1_ / 4); idx += 512) {
        const int pair = idx / (D1_ / 4);
        const int d4   = idx % (D1_ / 4);
        const int gp   = bpair0 + pair;
        const float* srow = seq + (size_t)gp * WL_ * D1_ + d4 * 4;
        float4 o4 = {0.f, 0.f, 0.f, 0.f};
        #pragma unroll
        for (int w = 0; w < WL_; ++w) {
            const float a = alpha_lds[pair * WL_ + w];
            const float4 s4 = *(const float4*)(srow + w * D1_);
            o4.x += a * s4.x; o4.y += a * s4.y;
            o4.z += a * s4.z; o4.w += a * s4.w;
        }
        *(float4*)(out + (size_t)gp * D1_ + d4 * 4) = o4;
    }
}

extern "C" void kernel_launch(void* const* d_in, const int* in_sizes, int n_in,
                              void* d_out, int out_size, void* d_ws, size_t ws_size,
                              hipStream_t stream) {
    const float* seq   = (const float*)d_in[0];
    const float* vec   = (const float*)d_in[1];
    const int*   masks = (const int*)d_in[2];
    const float* W     = (const float*)d_in[3];
    const float* b     = (const float*)d_in[4];
    const float* v     = (const float*)d_in[5];
    float* out = (float*)d_out;

    prep<<<(TOT_CHUNKS + 255) / 256, 256, 0, stream>>>(seq, vec, W, b);
    attn_mfma<<<NBLK, 512, 0, stream>>>(seq, masks, v, out);
}

// Round 4
// 274.190 us; speedup vs baseline: 2.4097x; 1.0306x over previous
//
#include <hip/hip_runtime.h>
#include <math.h>

#define NEG_INF -1000000000.0f

// Problem constants
#define B_   32
#define S_   128
#define WL_  20
#define D1_  300
#define D2_  300
#define OUT_ 300
#define BS_  (B_ * S_)          // 4096 (b,s) pairs
#define PPB  4                   // pairs per block
#define NBLK (BS_ / PPB)         // 1024 blocks
#define BM   80                  // 4 pairs * 20 rows
#define BN   320                 // 300 padded to 320
#define KA   320                 // padded K per half (seq | vec)
#define KS_  20                  // 20 k-steps of 32 over K=640

typedef __attribute__((ext_vector_type(8))) short bf16x8;
typedef __attribute__((ext_vector_type(4))) short short4v;
typedef __attribute__((ext_vector_type(4))) float f32x4;

// bf16 operand buffers rebuilt by prep each call
__device__ short g_Apre[(size_t)BS_ * WL_ * KA];  // [81920][320] seq bf16 (k-pad 0)
__device__ short g_vecb[(size_t)BS_ * KA];        // [4096][320]  vec bf16, [319]=1.0
__device__ short g_Wb[(size_t)BN * (2 * KA)];     // [320][640]   [Ws|0|Wv|0|bias]

__device__ inline short f2bf(float f) {
    unsigned u = __float_as_uint(f);
    u += 0x7FFFu + ((u >> 16) & 1u);   // RNE
    return (short)(u >> 16);
}

#define SEQ4 (BS_ * WL_ * (KA / 4))    // 6,553,600 float4->short4 tasks
#define VEC4 (BS_ * (KA / 4))          // 327,680
#define WEL  (BN * 2 * KA)             // 204,800 scalar tasks
#define TOTP (SEQ4 + VEC4 + WEL)

__global__ __launch_bounds__(256) void prep(
    const float* __restrict__ seq, const float* __restrict__ vec,
    const float* __restrict__ W,   const float* __restrict__ bias)
{
    const int id = blockIdx.x * 256 + threadIdx.x;
    if (id >= TOTP) return;
    if (id < SEQ4) {
        const int row = id / (KA / 4), c = id % (KA / 4), k = c * 4;
        short4v o4 = {0, 0, 0, 0};
        if (k < D1_) {   // chunks never straddle 300 (300%4==0)
            const float4 v = *(const float4*)(seq + (size_t)row * D1_ + k);
            o4.x = f2bf(v.x); o4.y = f2bf(v.y); o4.z = f2bf(v.z); o4.w = f2bf(v.w);
        }
        *(short4v*)(g_Apre + (size_t)row * KA + k) = o4;
    } else if (id < SEQ4 + VEC4) {
        const int idv = id - SEQ4;
        const int p = idv / (KA / 4), c = idv % (KA / 4), k = c * 4;
        short4v o4 = {0, 0, 0, 0};
        if (k < D2_) {
            const float4 v = *(const float4*)(vec + (size_t)p * D2_ + k);
            o4.x = f2bf(v.x); o4.y = f2bf(v.y); o4.z = f2bf(v.z); o4.w = f2bf(v.w);
        } else if (k == KA - 4) {
            o4.w = (short)0x3F80;      // 1.0 bf16 at col 319 (bias column)
        }
        *(short4v*)(g_vecb + (size_t)p * KA + k) = o4;
    } else {
        const int idw = id - SEQ4 - VEC4;
        const int o = idw / (2 * KA), kk = idw % (2 * KA);
        short val = 0;
        if (o < OUT_) {
            if (kk < D1_)                       val = f2bf(W[(size_t)o * (D1_ + D2_) + kk]);
            else if (kk >= KA && kk < KA + D2_) val = f2bf(W[(size_t)o * (D1_ + D2_) + D1_ + (kk - KA)]);
            else if (kk == 2 * KA - 1)          val = f2bf(bias[o]);
        }
        g_Wb[(size_t)o * (2 * KA) + kk] = val;
    }
}

__global__ __launch_bounds__(256, 2) void attn_mfma(
    const float* __restrict__ seq,   // fp32, for exact weighted-sum epilogue
    const int*   __restrict__ masks,
    const float* __restrict__ vvec,
    float*       __restrict__ out)
{
    __shared__ float sp[4][BM];
    __shared__ float score_lds[BM];
    __shared__ float alpha_lds[BM];

    const int tid  = threadIdx.x;
    const int lane = tid & 63;
    const int wn   = tid >> 6;      // 0..3 — wave owns cols [wn*80, wn*80+80)
    const int ln15 = lane & 15;
    const int q    = lane >> 4;     // 0..3 — k-quad within fragment
    const int bpair0 = blockIdx.x * PPB;

    f32x4 acc[5][5];
    #pragma unroll
    for (int i = 0; i < 5; ++i)
        #pragma unroll
        for (int j = 0; j < 5; ++j) acc[i][j] = {0.f, 0.f, 0.f, 0.f};

    // Per-fragment global base pointers (16B-contiguous fragments; K-loop adds
    // only an immediate offset ks*64B — zero per-kstep VALU).
    const short* pB[5];
    const short* pA[5];
    const short* pV[5];
    #pragma unroll
    for (int j = 0; j < 5; ++j) {
        const int o = wn * 80 + j * 16 + ln15;
        pB[j] = g_Wb + (size_t)o * (2 * KA) + q * 8;
    }
    #pragma unroll
    for (int i = 0; i < 5; ++i) {
        const int r = i * 16 + ln15;               // 0..79
        pA[i] = g_Apre + (size_t)(bpair0 * WL_ + r) * KA + q * 8;
        pV[i] = g_vecb + (size_t)(bpair0 + r / WL_) * KA + q * 8;
    }

    // Barrier-free K-loop: 10 global_load_dwordx4 + 25 MFMA per kstep,
    // fully unrolled so the compiler software-pipelines with vmcnt(N).
    #pragma unroll
    for (int ks = 0; ks < KS_; ++ks) {
        bf16x8 a[5], b[5];
        #pragma unroll
        for (int i = 0; i < 5; ++i)
            a[i] = (ks < 10) ? *(const bf16x8*)(pA[i] + ks * 32)
                             : *(const bf16x8*)(pV[i] + (ks - 10) * 32);
        #pragma unroll
        for (int j = 0; j < 5; ++j)
            b[j] = *(const bf16x8*)(pB[j] + ks * 32);
        #pragma unroll
        for (int i = 0; i < 5; ++i)
            #pragma unroll
            for (int j = 0; j < 5; ++j)
                acc[i][j] = __builtin_amdgcn_mfma_f32_16x16x32_bf16(a[i], b[j], acc[i][j], 0, 0, 0);
    }

    // ---- epilogue: score[r] = sum_o tanh(lin) * v[o] (bias folded into lin) ----
    float vj[5];
    #pragma unroll
    for (int j = 0; j < 5; ++j) {
        const int o = wn * 80 + j * 16 + ln15;
        vj[j] = (o < OUT_) ? vvec[o] : 0.f;
    }
    #pragma unroll
    for (int i = 0; i < 5; ++i) {
        float rs[4] = {0.f, 0.f, 0.f, 0.f};
        #pragma unroll
        for (int j = 0; j < 5; ++j) {
            #pragma unroll
            for (int r = 0; r < 4; ++r) {
                const float x = acc[i][j][r];
                const float e = __expf(2.f * x);           // tanh via exp
                rs[r] += (1.f - 2.f / (e + 1.f)) * vj[j];
            }
        }
        #pragma unroll
        for (int r = 0; r < 4; ++r) {
            float s = rs[r];
            s += __shfl_xor(s, 1, 64);
            s += __shfl_xor(s, 2, 64);
            s += __shfl_xor(s, 4, 64);
            s += __shfl_xor(s, 8, 64);                     // sum 16 cols of tile
            if (ln15 == 0) sp[wn][i * 16 + q * 4 + r] = s;
        }
    }
    __syncthreads();
    if (tid < BM) score_lds[tid] = sp[0][tid] + sp[1][tid] + sp[2][tid] + sp[3][tid];
    __syncthreads();

    // ---- masked softmax, one thread per pair ----
    if (tid < PPB) {
        const int gp = bpair0 + tid;
        float sc[WL_];
        float m = -INFINITY;
        #pragma unroll
        for (int w = 0; w < WL_; ++w) {
            const int mk = masks[(size_t)gp * WL_ + w];
            float s = (mk == 0) ? NEG_INF : score_lds[tid * WL_ + w];
            sc[w] = s;
            m = fmaxf(m, s);
        }
        float sum = 0.f;
        #pragma unroll
        for (int w = 0; w < WL_; ++w) { sc[w] = __expf(sc[w] - m); sum += sc[w]; }
        const float inv = 1.f / sum;
        #pragma unroll
        for (int w = 0; w < WL_; ++w) alpha_lds[tid * WL_ + w] = sc[w] * inv;
    }
    __syncthreads();

    // ---- weighted sum from fp32 seq (L3-hot) ----
    for (int idx = tid; idx < PPB * (D1_ / 4); idx += 256) {
        const int pair = idx / (D1_ / 4);
        const int d4   = idx % (D1_ / 4);
        const int gp   = bpair0 + pair;
        const float* srow = seq + (size_t)gp * WL_ * D1_ + d4 * 4;
        float4 o4 = {0.f, 0.f, 0.f, 0.f};
        #pragma unroll
        for (int w = 0; w < WL_; ++w) {
            const float a = alpha_lds[pair * WL_ + w];
            const float4 s4 = *(const float4*)(srow + w * D1_);
            o4.x += a * s4.x; o4.y += a * s4.y;
            o4.z += a * s4.z; o4.w += a * s4.w;
        }
        *(float4*)(out + (size_t)gp * D1_ + d4 * 4) = o4;
    }
}

extern "C" void kernel_launch(void* const* d_in, const int* in_sizes, int n_in,
                              void* d_out, int out_size, void* d_ws, size_t ws_size,
                              hipStream_t stream) {
    const float* seq   = (const float*)d_in[0];
    const float* vec   = (const float*)d_in[1];
    const int*   masks = (const int*)d_in[2];
    const float* W     = (const float*)d_in[3];
    const float* b     = (const float*)d_in[4];
    const float* v     = (const float*)d_in[5];
    float* out = (float*)d_out;

    prep<<<(TOTP + 255) / 256, 256, 0, stream>>>(seq, vec, W, b);
    attn_mfma<<<NBLK, 256, 0, stream>>>(seq, masks, v, out);
}

// Round 5
// 266.548 us; speedup vs baseline: 2.4788x; 1.0287x over previous
//
#include <hip/hip_runtime.h>
#include <math.h>

#define NEG_INF -1000000000.0f

// Problem constants
#define WL_  20
#define D1_  300
#define D2_  300
#define OUT_ 300
#define BS_  4096                 // (b,s) pairs
#define PPB  4                    // pairs per block
#define NBLK (BS_ / PPB)          // 1024 blocks
#define BM   80                   // rows per block = 5 M-tiles
#define KS   10                   // k-steps of 32 (K = 320, seq-half only)
#define FR   512                  // shorts per fragment slab [64 lanes][8]

typedef __attribute__((ext_vector_type(8))) short bf16x8;
typedef __attribute__((ext_vector_type(8))) short short8v;
typedef __attribute__((ext_vector_type(4))) float f32x4;

// Fragment-packed bf16 operands (every wave load = contiguous 1 KB)
__device__ short g_Apk[(size_t)NBLK * 5 * KS * FR];   // [blk][tile][ks][lane][8]  52.4 MB
__device__ short g_Bpk[KS * 20 * FR];                  // [ks][tile][lane][8]  Ws
__device__ short g_Vpk[256 * KS * FR];                 // [mtile][ks][lane][8] vec (+1.0 col)
__device__ short g_Wvpk[KS * 20 * FR];                 // [ks][tile][lane][8]  Wv (+bias col)
__device__ float g_vlin[(size_t)BS_ * 320];            // vec-side linear + bias, fp32

__device__ inline short f2bf(float f) {
    unsigned u = __float_as_uint(f);
    u += 0x7FFFu + ((u >> 16) & 1u);   // RNE
    return (short)(u >> 16);
}
__device__ inline float bf2f(short s) {
    return __uint_as_float(((unsigned)(unsigned short)s) << 16);
}

#define GA (NBLK * 5 * KS * 64)   // 3,276,800 fragment-groups (seq)
#define GV (256 * KS * 64)        // 163,840 (vec)
#define GB (KS * 20 * 64)         // 12,800 (Ws)
#define GT (GA + GV + GB + GB)

__global__ __launch_bounds__(256) void prep(
    const float* __restrict__ seq, const float* __restrict__ vec,
    const float* __restrict__ W,   const float* __restrict__ bias)
{
    const int id = blockIdx.x * 256 + threadIdx.x;
    if (id >= GT) return;
    short8v o8 = {0, 0, 0, 0, 0, 0, 0, 0};
    if (id < GA) {
        const int lane = id & 63, g = id >> 6;
        const int q = lane >> 4, l15 = lane & 15;
        const int ks = g % KS, t2 = g / KS;
        const int tile = t2 % 5, blk = t2 / 5;
        const int row = blk * BM + tile * 16 + l15;
        const int k0 = ks * 32 + q * 8;
        const float* s = seq + (size_t)row * D1_ + k0;
        if (k0 + 8 <= D1_) {
            const float4 u = *(const float4*)s;
            const float4 w2 = *(const float4*)(s + 4);
            o8[0] = f2bf(u.x);  o8[1] = f2bf(u.y);  o8[2] = f2bf(u.z);  o8[3] = f2bf(u.w);
            o8[4] = f2bf(w2.x); o8[5] = f2bf(w2.y); o8[6] = f2bf(w2.z); o8[7] = f2bf(w2.w);
        } else if (k0 < D1_) {
            #pragma unroll
            for (int e = 0; e < 8; ++e) if (k0 + e < D1_) o8[e] = f2bf(s[e]);
        }
        *(short8v*)(g_Apk + (size_t)id * 8) = o8;
    } else if (id < GA + GV) {
        const int id2 = id - GA;
        const int lane = id2 & 63, g = id2 >> 6;
        const int q = lane >> 4, l15 = lane & 15;
        const int ks = g % KS, mtile = g / KS;
        const int row = mtile * 16 + l15;          // pair index, < 4096
        const int k0 = ks * 32 + q * 8;
        const float* s = vec + (size_t)row * D2_ + k0;
        #pragma unroll
        for (int e = 0; e < 8; ++e) {
            const int k = k0 + e;
            if (k < D2_) o8[e] = f2bf(s[e]);
            else if (k == 319) o8[e] = (short)0x3F80;   // 1.0 (bias column)
        }
        *(short8v*)(g_Vpk + (size_t)id2 * 8) = o8;
    } else if (id < GA + GV + GB) {
        const int id3 = id - GA - GV;
        const int lane = id3 & 63, g = id3 >> 6;
        const int q = lane >> 4, l15 = lane & 15;
        const int ks = g / 20, tile = g % 20;
        const int o = tile * 16 + l15, k0 = ks * 32 + q * 8;
        if (o < OUT_) {
            #pragma unroll
            for (int e = 0; e < 8; ++e) {
                const int k = k0 + e;
                if (k < D1_) o8[e] = f2bf(W[(size_t)o * (D1_ + D2_) + k]);
            }
        }
        *(short8v*)(g_Bpk + (size_t)id3 * 8) = o8;
    } else {
        const int id4 = id - GA - GV - GB;
        const int lane = id4 & 63, g = id4 >> 6;
        const int q = lane >> 4, l15 = lane & 15;
        const int ks = g / 20, tile = g % 20;
        const int o = tile * 16 + l15, k0 = ks * 32 + q * 8;
        if (o < OUT_) {
            #pragma unroll
            for (int e = 0; e < 8; ++e) {
                const int k = k0 + e;
                if (k < D2_)        o8[e] = f2bf(W[(size_t)o * (D1_ + D2_) + D1_ + k]);
                else if (k == 319)  o8[e] = f2bf(bias[o]);
            }
        }
        *(short8v*)(g_Wvpk + (size_t)id4 * 8) = o8;
    }
}

// vlin[row][col] = vec . Wv + bias   (4096 x 320, K=320)
__global__ __launch_bounds__(64) void vlin_kernel() {
    const int mtile = blockIdx.x;           // 0..255
    const int lane = threadIdx.x;
    const int q = lane >> 4, l15 = lane & 15;
    f32x4 acc[20];
    #pragma unroll
    for (int j = 0; j < 20; ++j) acc[j] = {0.f, 0.f, 0.f, 0.f};
    const short* pa = g_Vpk + (size_t)mtile * KS * FR + lane * 8;
    const short* pb = g_Wvpk + lane * 8;
    #pragma unroll
    for (int ks = 0; ks < KS; ++ks) {
        const bf16x8 a = *(const bf16x8*)pa; pa += FR;
        #pragma unroll
        for (int j = 0; j < 20; ++j) {
            const bf16x8 b = *(const bf16x8*)(pb + j * FR);
            acc[j] = __builtin_amdgcn_mfma_f32_16x16x32_bf16(a, b, acc[j], 0, 0, 0);
        }
        pb += 20 * FR;
    }
    const int row0 = mtile * 16 + q * 4;
    #pragma unroll
    for (int j = 0; j < 20; ++j)
        #pragma unroll
        for (int r = 0; r < 4; ++r)
            g_vlin[(size_t)(row0 + r) * 320 + j * 16 + l15] = acc[j][r];
}

__global__ __launch_bounds__(256, 2) void attn_main(
    const int*   __restrict__ masks,
    const float* __restrict__ vvec,
    float*       __restrict__ out)
{
    __shared__ short Am[5 * KS * FR];     // 51,200 B — bf16 A mirror for weighted sum
    __shared__ float sp[4][BM];
    __shared__ float score_lds[BM];
    __shared__ float alpha_lds[BM];

    const int tid  = threadIdx.x;
    const int lane = tid & 63;
    const int wn   = tid >> 6;            // wave owns n-tiles wn*5..wn*5+4 (cols wn*80..)
    const int q    = lane >> 4;
    const int l15  = lane & 15;
    const int blk  = blockIdx.x;

    f32x4 acc[5][5];
    #pragma unroll
    for (int i = 0; i < 5; ++i)
        #pragma unroll
        for (int j = 0; j < 5; ++j) acc[i][j] = {0.f, 0.f, 0.f, 0.f};

    const short* pa[5];
    const short* pb[5];
    #pragma unroll
    for (int i = 0; i < 5; ++i)
        pa[i] = g_Apk + ((size_t)blk * 5 + i) * KS * FR + lane * 8;
    #pragma unroll
    for (int j = 0; j < 5; ++j)
        pb[j] = g_Bpk + (size_t)(wn * 5 + j) * FR + lane * 8;

    // depth-2 register pipeline: loads for ks+1 issue before MFMAs of ks
    bf16x8 ab[2][5], bb[2][5];
    #pragma unroll
    for (int i = 0; i < 5; ++i) { ab[0][i] = *(const bf16x8*)pa[i]; pa[i] += FR; }
    #pragma unroll
    for (int j = 0; j < 5; ++j) { bb[0][j] = *(const bf16x8*)pb[j]; pb[j] += 20 * FR; }

    #pragma unroll
    for (int ks = 0; ks < KS; ++ks) {
        const int cur = ks & 1, nxt = cur ^ 1;
        if (ks + 1 < KS) {
            #pragma unroll
            for (int i = 0; i < 5; ++i) { ab[nxt][i] = *(const bf16x8*)pa[i]; pa[i] += FR; }
            #pragma unroll
            for (int j = 0; j < 5; ++j) { bb[nxt][j] = *(const bf16x8*)pb[j]; pb[j] += 20 * FR; }
        }
        if (wn == 0) {     // mirror A fragments to LDS for the weighted-sum epilogue
            #pragma unroll
            for (int i = 0; i < 5; ++i)
                *(bf16x8*)(Am + ((i * KS + ks) * 64 + lane) * 8) = ab[cur][i];
        }
        #pragma unroll
        for (int i = 0; i < 5; ++i)
            #pragma unroll
            for (int j = 0; j < 5; ++j)
                acc[i][j] = __builtin_amdgcn_mfma_f32_16x16x32_bf16(ab[cur][i], bb[cur][j], acc[i][j], 0, 0, 0);
    }

    // ---- epilogue: lin = acc + vlin; score[r] = sum_o tanh(lin) * v[o] ----
    float vj[5];
    #pragma unroll
    for (int j = 0; j < 5; ++j) {
        const int col = wn * 80 + j * 16 + l15;
        vj[j] = (col < OUT_) ? vvec[col] : 0.f;
    }
    #pragma unroll
    for (int i = 0; i < 5; ++i) {
        #pragma unroll
        for (int r = 0; r < 4; ++r) {
            const int row  = i * 16 + q * 4 + r;       // 0..79
            const int pair = row / 20;
            const float* vl = g_vlin + (size_t)(blk * PPB + pair) * 320 + wn * 80 + l15;
            float s = 0.f;
            #pragma unroll
            for (int j = 0; j < 5; ++j) {
                const float x = acc[i][j][r] + vl[j * 16];
                const float e = __expf(2.f * x);       // tanh(x) = 1 - 2/(e^{2x}+1)
                s += (1.f - 2.f / (e + 1.f)) * vj[j];
            }
            s += __shfl_xor(s, 1, 64);
            s += __shfl_xor(s, 2, 64);
            s += __shfl_xor(s, 4, 64);
            s += __shfl_xor(s, 8, 64);                 // sum over 16 cols of tile
            if (l15 == 0) sp[wn][row] = s;
        }
    }
    __syncthreads();
    if (tid < BM) score_lds[tid] = sp[0][tid] + sp[1][tid] + sp[2][tid] + sp[3][tid];
    __syncthreads();

    // ---- masked softmax, one thread per pair ----
    if (tid < PPB) {
        const int gp = blk * PPB + tid;
        float sc[WL_];
        float m = -INFINITY;
        #pragma unroll
        for (int w = 0; w < WL_; ++w) {
            const int mk = masks[(size_t)gp * WL_ + w];
            float s = (mk == 0) ? NEG_INF : score_lds[tid * WL_ + w];
            sc[w] = s;
            m = fmaxf(m, s);
        }
        float sum = 0.f;
        #pragma unroll
        for (int w = 0; w < WL_; ++w) { sc[w] = __expf(sc[w] - m); sum += sc[w]; }
        const float inv = 1.f / sum;
        #pragma unroll
        for (int w = 0; w < WL_; ++w) alpha_lds[tid * WL_ + w] = sc[w] * inv;
    }
    __syncthreads();

    // ---- weighted sum from the bf16 LDS mirror (no global seq re-read) ----
    // thread handles 8 consecutive d for one pair: idx = p*38 + chunk
    if (tid < PPB * 38) {
        const int p = tid / 38, ch = tid % 38;
        const int ks2 = ch >> 2, q2 = ch & 3;
        float o8[8] = {0.f, 0.f, 0.f, 0.f, 0.f, 0.f, 0.f, 0.f};
        #pragma unroll
        for (int w = 0; w < WL_; ++w) {
            const int row = p * WL_ + w;
            const int tile = row >> 4, l = row & 15;
            const bf16x8 s8 = *(const bf16x8*)(Am + ((tile * KS + ks2) * 64 + q2 * 16 + l) * 8);
            const float a = alpha_lds[row];
            #pragma unroll
            for (int e = 0; e < 8; ++e) o8[e] += a * bf2f(s8[e]);
        }
        const int d0 = ch * 8, gp = blk * PPB + p;
        float* dst = out + (size_t)gp * OUT_ + d0;
        if (d0 + 8 <= OUT_) {
            *(float4*)dst       = {o8[0], o8[1], o8[2], o8[3]};
            *(float4*)(dst + 4) = {o8[4], o8[5], o8[6], o8[7]};
        } else {                                   // d0 == 296: last 4 only
            *(float4*)dst = {o8[0], o8[1], o8[2], o8[3]};
        }
    }
}

extern "C" void kernel_launch(void* const* d_in, const int* in_sizes, int n_in,
                              void* d_out, int out_size, void* d_ws, size_t ws_size,
                              hipStream_t stream) {
    const float* seq   = (const float*)d_in[0];
    const float* vec   = (const float*)d_in[1];
    const int*   masks = (const int*)d_in[2];
    const float* W     = (const float*)d_in[3];
    const float* b     = (const float*)d_in[4];
    const float* v     = (const float*)d_in[5];
    float* out = (float*)d_out;

    prep<<<(GT + 255) / 256, 256, 0, stream>>>(seq, vec, W, b);
    vlin_kernel<<<256, 64, 0, stream>>>();
    attn_main<<<NBLK, 256, 0, stream>>>(masks, v, out);
}

// Round 6
// 252.409 us; speedup vs baseline: 2.6176x; 1.0560x over previous
//
#include <hip/hip_runtime.h>
#include <math.h>

#define NEG_INF -1000000000.0f

// Problem constants
#define WL_  20
#define D1_  300
#define D2_  300
#define OUT_ 300
#define BS_  4096                 // (b,s) pairs
#define PPB  4                    // pairs per block
#define NBLK (BS_ / PPB)          // 1024 blocks
#define BM   80                   // rows per block = 5 M-tiles
#define KS   10                   // k-steps of 32 (K = 320, seq-half)
#define FR   512                  // shorts per fragment slab [64 lanes][8]

typedef __attribute__((ext_vector_type(8))) short bf16x8;
typedef __attribute__((ext_vector_type(8))) short short8v;
typedef __attribute__((ext_vector_type(4))) float f32x4;
typedef __attribute__((ext_vector_type(4))) unsigned int uint4v;

// Small fragment-packed bf16 operands (L2-resident), rebuilt each call
__device__ short g_Bpk[KS * 20 * FR];        // [ks][tile][lane][8]  Ws (zero-pad k>=300)
__device__ short g_Vpk[256 * KS * FR];       // [mtile][ks][lane][8] vec (+1.0 col @319)
__device__ short g_Wvpk[KS * 20 * FR];       // [ks][tile][lane][8]  Wv (+bias col @319)
__device__ float g_vlin[(size_t)BS_ * 320];  // vec-side linear + bias, fp32

__device__ inline short f2bf(float f) {
    unsigned u = __float_as_uint(f);
    u += 0x7FFFu + ((u >> 16) & 1u);   // RNE
    return (short)(u >> 16);
}
__device__ inline float bf2f(short s) {
    return __uint_as_float(((unsigned)(unsigned short)s) << 16);
}

#define GV (256 * KS * 64)        // 163,840 vec fragment-groups
#define GB (KS * 20 * 64)         // 12,800  W fragment-groups
#define GT (GV + GB + GB)

__global__ __launch_bounds__(256) void prep_small(
    const float* __restrict__ vec, const float* __restrict__ W,
    const float* __restrict__ bias)
{
    const int id = blockIdx.x * 256 + threadIdx.x;
    if (id >= GT) return;
    short8v o8 = {0, 0, 0, 0, 0, 0, 0, 0};
    if (id < GV) {
        const int lane = id & 63, g = id >> 6;
        const int q = lane >> 4, l15 = lane & 15;
        const int ks = g % KS, mtile = g / KS;
        const int row = mtile * 16 + l15;          // pair index < 4096
        const int k0 = ks * 32 + q * 8;
        const float* s = vec + (size_t)row * D2_ + k0;
        #pragma unroll
        for (int e = 0; e < 8; ++e) {
            const int k = k0 + e;
            if (k < D2_) o8[e] = f2bf(s[e]);
            else if (k == 319) o8[e] = (short)0x3F80;   // 1.0 (bias column)
        }
        *(short8v*)(g_Vpk + (size_t)id * 8) = o8;
    } else if (id < GV + GB) {
        const int id3 = id - GV;
        const int lane = id3 & 63, g = id3 >> 6;
        const int q = lane >> 4, l15 = lane & 15;
        const int ks = g / 20, tile = g % 20;
        const int o = tile * 16 + l15, k0 = ks * 32 + q * 8;
        if (o < OUT_) {
            #pragma unroll
            for (int e = 0; e < 8; ++e) {
                const int k = k0 + e;
                if (k < D1_) o8[e] = f2bf(W[(size_t)o * (D1_ + D2_) + k]);
            }
        }
        *(short8v*)(g_Bpk + (size_t)id3 * 8) = o8;
    } else {
        const int id4 = id - GV - GB;
        const int lane = id4 & 63, g = id4 >> 6;
        const int q = lane >> 4, l15 = lane & 15;
        const int ks = g / 20, tile = g % 20;
        const int o = tile * 16 + l15, k0 = ks * 32 + q * 8;
        if (o < OUT_) {
            #pragma unroll
            for (int e = 0; e < 8; ++e) {
                const int k = k0 + e;
                if (k < D2_)        o8[e] = f2bf(W[(size_t)o * (D1_ + D2_) + D1_ + k]);
                else if (k == 319)  o8[e] = f2bf(bias[o]);
            }
        }
        *(short8v*)(g_Wvpk + (size_t)id4 * 8) = o8;
    }
}

// vlin[row][col] = vec . Wv + bias   (4096 x 320, K=320)
__global__ __launch_bounds__(64) void vlin_kernel() {
    const int mtile = blockIdx.x;           // 0..255
    const int lane = threadIdx.x;
    const int q = lane >> 4, l15 = lane & 15;
    f32x4 acc[20];
    #pragma unroll
    for (int j = 0; j < 20; ++j) acc[j] = {0.f, 0.f, 0.f, 0.f};
    const short* pa = g_Vpk + (size_t)mtile * KS * FR + lane * 8;
    const short* pb = g_Wvpk + lane * 8;
    #pragma unroll
    for (int ks = 0; ks < KS; ++ks) {
        const bf16x8 a = *(const bf16x8*)pa; pa += FR;
        #pragma unroll
        for (int j = 0; j < 20; ++j) {
            const bf16x8 b = *(const bf16x8*)(pb + j * FR);
            acc[j] = __builtin_amdgcn_mfma_f32_16x16x32_bf16(a, b, acc[j], 0, 0, 0);
        }
        pb += 20 * FR;
    }
    const int row0 = mtile * 16 + q * 4;
    #pragma unroll
    for (int j = 0; j < 20; ++j)
        #pragma unroll
        for (int r = 0; r < 4; ++r)
            g_vlin[(size_t)(row0 + r) * 320 + j * 16 + l15] = acc[j][r];
}

__global__ __launch_bounds__(256, 2) void attn_fused(
    const float* __restrict__ seq,   // fp32 [4096,20,300]
    const int*   __restrict__ masks,
    const float* __restrict__ vvec,
    float*       __restrict__ out)
{
    __shared__ short Am[5 * KS * FR];     // 51,200 B — bf16 A in fragment layout
    __shared__ float sp[4][BM];
    __shared__ float score_lds[BM];
    __shared__ float alpha_lds[BM];       // total 53,120 B

    const int tid  = threadIdx.x;
    const int lane = tid & 63;
    const int wv   = tid >> 6;            // 0..3
    const int q    = lane >> 4;
    const int l15  = lane & 15;
    const int blk  = blockIdx.x;

    // ---- Phase 1: fp32 seq tile -> bf16 fragment slabs in LDS ----
    // One wave-task = one (tile, ks) slab: lane (q,l15) covers row tile*16+l15,
    // k = ks*32 + q*8 .. +8. Global: 4 q-chunks x 128 B per row (coalesced-ish);
    // LDS write: base + lane*16 (perfectly contiguous, conflict-free).
    {
        const float* sbase = seq + (size_t)blk * BM * D1_;
        for (int s = wv; s < 50; s += 4) {
            const int tile = s / KS, ks = s % KS;
            const int row = tile * 16 + l15;
            const int k0 = ks * 32 + q * 8;
            const float* p = sbase + (size_t)row * D1_ + k0;
            float4 fa = {0.f, 0.f, 0.f, 0.f}, fb = {0.f, 0.f, 0.f, 0.f};
            if (k0 < 296) { fa = *(const float4*)p; fb = *(const float4*)(p + 4); }
            else if (k0 == 296) { fa = *(const float4*)p; }
            // round-half-up fp32->bf16, pack pairs with v_perm
            unsigned u0 = __float_as_uint(fa.x) + 0x8000u;
            unsigned u1 = __float_as_uint(fa.y) + 0x8000u;
            unsigned u2 = __float_as_uint(fa.z) + 0x8000u;
            unsigned u3 = __float_as_uint(fa.w) + 0x8000u;
            unsigned u4 = __float_as_uint(fb.x) + 0x8000u;
            unsigned u5 = __float_as_uint(fb.y) + 0x8000u;
            unsigned u6 = __float_as_uint(fb.z) + 0x8000u;
            unsigned u7 = __float_as_uint(fb.w) + 0x8000u;
            uint4v w;
            w.x = __builtin_amdgcn_perm(u1, u0, 0x07060302u);
            w.y = __builtin_amdgcn_perm(u3, u2, 0x07060302u);
            w.z = __builtin_amdgcn_perm(u5, u4, 0x07060302u);
            w.w = __builtin_amdgcn_perm(u7, u6, 0x07060302u);
            *(uint4v*)(Am + ((size_t)s * 64 + lane) * 8) = w;
        }
    }
    __syncthreads();

    // ---- Phase 2: barrier-free GEMM. A from LDS, B from L2 (frag-packed) ----
    f32x4 acc[5][5];
    #pragma unroll
    for (int i = 0; i < 5; ++i)
        #pragma unroll
        for (int j = 0; j < 5; ++j) acc[i][j] = {0.f, 0.f, 0.f, 0.f};

    const short* pb[5];
    #pragma unroll
    for (int j = 0; j < 5; ++j)
        pb[j] = g_Bpk + (size_t)(wv * 5 + j) * FR + lane * 8;

    #pragma unroll
    for (int ks = 0; ks < KS; ++ks) {
        bf16x8 a[5], b[5];
        #pragma unroll
        for (int i = 0; i < 5; ++i)
            a[i] = *(const bf16x8*)(Am + (((size_t)i * KS + ks) * 64 + lane) * 8);
        #pragma unroll
        for (int j = 0; j < 5; ++j)
            b[j] = *(const bf16x8*)(pb[j] + (size_t)ks * 20 * FR);
        #pragma unroll
        for (int i = 0; i < 5; ++i)
            #pragma unroll
            for (int j = 0; j < 5; ++j)
                acc[i][j] = __builtin_amdgcn_mfma_f32_16x16x32_bf16(a[i], b[j], acc[i][j], 0, 0, 0);
    }

    // ---- epilogue: lin = acc + vlin; score[r] = sum_o tanh(lin) * v[o] ----
    float vj[5];
    #pragma unroll
    for (int j = 0; j < 5; ++j) {
        const int col = wv * 80 + j * 16 + l15;
        vj[j] = (col < OUT_) ? vvec[col] : 0.f;
    }
    #pragma unroll
    for (int i = 0; i < 5; ++i) {
        #pragma unroll
        for (int r = 0; r < 4; ++r) {
            const int row  = i * 16 + q * 4 + r;       // 0..79
            const int pair = row / 20;
            const float* vl = g_vlin + (size_t)(blk * PPB + pair) * 320 + wv * 80 + l15;
            float s = 0.f;
            #pragma unroll
            for (int j = 0; j < 5; ++j) {
                const float x = acc[i][j][r] + vl[j * 16];
                const float e = __expf(2.f * x);       // tanh(x) = 1 - 2/(e^{2x}+1)
                s += (1.f - 2.f / (e + 1.f)) * vj[j];
            }
            s += __shfl_xor(s, 1, 64);
            s += __shfl_xor(s, 2, 64);
            s += __shfl_xor(s, 4, 64);
            s += __shfl_xor(s, 8, 64);                 // sum 16 cols of tile
            if (l15 == 0) sp[wv][row] = s;
        }
    }
    __syncthreads();
    if (tid < BM) score_lds[tid] = sp[0][tid] + sp[1][tid] + sp[2][tid] + sp[3][tid];
    __syncthreads();

    // ---- masked softmax, one thread per pair ----
    if (tid < PPB) {
        const int gp = blk * PPB + tid;
        float sc[WL_];
        float m = -INFINITY;
        #pragma unroll
        for (int w = 0; w < WL_; ++w) {
            const int mk = masks[(size_t)gp * WL_ + w];
            float s = (mk == 0) ? NEG_INF : score_lds[tid * WL_ + w];
            sc[w] = s;
            m = fmaxf(m, s);
        }
        float sum = 0.f;
        #pragma unroll
        for (int w = 0; w < WL_; ++w) { sc[w] = __expf(sc[w] - m); sum += sc[w]; }
        const float inv = 1.f / sum;
        #pragma unroll
        for (int w = 0; w < WL_; ++w) alpha_lds[tid * WL_ + w] = sc[w] * inv;
    }
    __syncthreads();

    // ---- weighted sum from the bf16 LDS fragments ----
    if (tid < PPB * 38) {
        const int p = tid / 38, ch = tid % 38;
        const int ks2 = ch >> 2, q2 = ch & 3;
        float o8[8] = {0.f, 0.f, 0.f, 0.f, 0.f, 0.f, 0.f, 0.f};
        #pragma unroll
        for (int w = 0; w < WL_; ++w) {
            const int row = p * WL_ + w;
            const int tile = row >> 4, l = row & 15;
            const bf16x8 s8 = *(const bf16x8*)(Am + (((size_t)tile * KS + ks2) * 64 + q2 * 16 + l) * 8);
            const float a = alpha_lds[row];
            #pragma unroll
            for (int e = 0; e < 8; ++e) o8[e] += a * bf2f(s8[e]);
        }
        const int d0 = ch * 8, gp = blk * PPB + p;
        float* dst = out + (size_t)gp * OUT_ + d0;
        if (d0 + 8 <= OUT_) {
            *(float4*)dst       = {o8[0], o8[1], o8[2], o8[3]};
            *(float4*)(dst + 4) = {o8[4], o8[5], o8[6], o8[7]};
        } else {                                   // d0 == 296: last 4 only
            *(float4*)dst = {o8[0], o8[1], o8[2], o8[3]};
        }
    }
}

extern "C" void kernel_launch(void* const* d_in, const int* in_sizes, int n_in,
                              void* d_out, int out_size, void* d_ws, size_t ws_size,
                              hipStream_t stream) {
    const float* seq   = (const float*)d_in[0];
    const float* vec   = (const float*)d_in[1];
    const int*   masks = (const int*)d_in[2];
    const float* W     = (const float*)d_in[3];
    const float* b     = (const float*)d_in[4];
    const float* v     = (const float*)d_in[5];
    float* out = (float*)d_out;

    prep_small<<<(GT + 255) / 256, 256, 0, stream>>>(vec, W, b);
    vlin_kernel<<<256, 64, 0, stream>>>();
    attn_fused<<<NBLK, 256, 0, stream>>>(seq, masks, v, out);
}